// Round 6
// baseline (1190.981 us; speedup 1.0000x reference)
//
#include <hip/hip_runtime.h>
#include <utility>

// SO(3) bispectrum via per-(l1,l2)-pair bf16 MFMA GEMMs.
// out[b,t] = sum_{m1,m2,m} cg[t,m1,m2,m] * F1[b,m1] * F2[b,m2] * F3[b,m]
// R6: A-frags (G = F1*F2) built in registers per wave (no LDS G stage, 2 barriers/pair),
//     P tile in LDS with odd stride 97 (bank-conflict-free), epilogue writes direct to
//     global. 256 thr / 4 waves / 64 rows per block; LDS 45.6 KB -> 3 blocks/CU.

#define LMAXV 8
#define NCOEFV 81
#define NTRIV 215
#define CGS 4913          // 17*17*17
#define NPAIRS 45
#define THREADS 256
#define PSTR 97           // fp32 row stride of P tile (odd -> banks spread)

typedef float f32x4 __attribute__((ext_vector_type(4)));
typedef __bf16 bf16x8 __attribute__((ext_vector_type(8)));

struct PairInfo {
    int l1, l2, D1, D2, K, Kpad, KS, lmin, nl, N, NT, tstart, cpbase;
};
struct PairTab { PairInfo p[NPAIRS]; int nft; int cptot; };

constexpr PairTab make_pairs() {
    PairTab tb{};
    int idx = 0, t = 0, cpb = 0, ft = 0;
    for (int l1 = 0; l1 <= LMAXV; ++l1)
        for (int l2 = l1; l2 <= LMAXV; ++l2) {
            PairInfo pi{};
            pi.l1 = l1; pi.l2 = l2;
            pi.D1 = 2 * l1 + 1; pi.D2 = 2 * l2 + 1;
            pi.K = pi.D1 * pi.D2;
            pi.Kpad = (pi.K + 31) & ~31;
            pi.KS = pi.Kpad / 32;
            pi.lmin = l2 - l1;
            int lmax = (l1 + l2 < LMAXV) ? (l1 + l2) : LMAXV;
            pi.nl = lmax - pi.lmin + 1;
            int N = 0;
            for (int l = pi.lmin; l <= lmax; ++l) N += 2 * l + 1;
            pi.N = N;
            pi.NT = (N + 15) / 16;
            pi.tstart = t;
            t += pi.nl;
            pi.cpbase = cpb;
            cpb += pi.NT * pi.KS * 512;   // elements (bf16)
            ft += pi.NT * pi.KS;
            tb.p[idx++] = pi;
        }
    tb.nft = ft; tb.cptot = cpb;
    return tb;
}
constexpr PairTab PT = make_pairs();
__device__ const PairTab d_PT = make_pairs();   // runtime-indexable copy for prep

static_assert(PT.p[NPAIRS - 1].tstart + PT.p[NPAIRS - 1].nl == NTRIV, "triple count");
static_assert(PT.p[NPAIRS - 1].Kpad == 320, "max Kpad");

__device__ __forceinline__ unsigned short f2bf(float f) {   // RNE f32 -> bf16 bits
    unsigned u = __float_as_uint(f);
    return (unsigned short)((u + 0x7fffu + ((u >> 16) & 1u)) >> 16);
}

// ---- prep: pack cg (fp32) into fragment-linear bf16 Cp in d_ws, zero-padded.
// One 64-thread block per (pair, nt, ks) fragment tile. Lane l holds
// B[k = ks*32 + (l>>4)*8 + i][n = nt*16 + (l&15)], 8 bf16 = 16B, stored linearly.
// (Layout validated in R5: absmax 4.0 pass.)
__global__ __launch_bounds__(64) void prep_kernel(const float* __restrict__ cg,
                                                  unsigned short* __restrict__ cp) {
    int bid = blockIdx.x, lane = threadIdx.x;
    int p = 0, base = 0;
    while (p < NPAIRS - 1 && bid >= base + d_PT.p[p].NT * d_PT.p[p].KS) {
        base += d_PT.p[p].NT * d_PT.p[p].KS; ++p;
    }
    PairInfo pi = d_PT.p[p];
    int local = bid - base;
    int nt = local / pi.KS, ks = local - nt * pi.KS;
    int n = nt * 16 + (lane & 15);
    int kb = ks * 32 + (lane >> 4) * 8;
    int tl = -1, m = 0;
    if (n < pi.N) {
        int off = 0;
        for (int q = 0; q < pi.nl; ++q) {
            int D3 = 2 * (pi.lmin + q) + 1;
            if (n < off + D3) { tl = q; m = n - off; break; }
            off += D3;
        }
    }
    unsigned short vals[8];
#pragma unroll
    for (int i = 0; i < 8; ++i) {
        int k = kb + i;
        float v = 0.f;
        if (tl >= 0 && k < pi.K) {
            int m1 = k / pi.D2, m2 = k - (k / pi.D2) * pi.D2;
            v = cg[(long)(pi.tstart + tl) * CGS + (m1 * 17 + m2) * 17 + m];
        }
        vals[i] = f2bf(v);
    }
    *reinterpret_cast<bf16x8*>(cp + pi.cpbase + ((long)(nt * pi.KS + ks) * 64 + lane) * 8) =
        *reinterpret_cast<bf16x8*>(vals);
}

// ---- per-pair step inside the main kernel (all shapes compile-time)
template <int P>
__device__ __forceinline__ void pair_step(const float* xs, float* Ps,
                                          const unsigned short* __restrict__ cp,
                                          float* __restrict__ outg, int wave, int lane) {
    constexpr PairInfo pi = PT.p[P];
    constexpr int D2 = pi.D2, K = pi.K, KS = pi.KS, NT = pi.NT;
    constexpr int XB1 = pi.l1 * pi.l1, XB2 = pi.l2 * pi.l2;
    const int tid = wave * 64 + lane;

    // A-frag build in registers: lane holds G[row][k], k = ks*32 + (lane>>4)*8 + i.
    // Runs in the same barrier-free region as the previous pair's epilogue.
    const int row = wave * 16 + (lane & 15);
    const int kq = (lane >> 4) * 8;
    const float* xr = xs + row * NCOEFV;
    bf16x8 af[KS];
#pragma unroll
    for (int ks = 0; ks < KS; ++ks) {
#pragma unroll
        for (int i = 0; i < 8; ++i) {
            const int k = ks * 32 + kq + i;
            float v = 0.f;
            if (k < K) {                       // predicated; B-pad is zeroed anyway
                const int m1 = k / D2, m2 = k - (k / D2) * D2;
                v = xr[XB1 + m1] * xr[XB2 + m2];
            }
            af[ks][i] = (__bf16)v;
        }
    }
    __syncthreads();  // (1) prev pair's epilogue P-reads done -> P writable
    {
        const bf16x8* cpf = (const bf16x8*)(cp + pi.cpbase);
        const int col = lane & 15;
        const int row0 = wave * 16 + ((lane >> 4) << 2);  // C/D: col=lane&15, row=(lane>>4)*4+r
#pragma unroll
        for (int nt = 0; nt < NT; ++nt) {
            f32x4 acc = {0.f, 0.f, 0.f, 0.f};
#pragma unroll
            for (int ks = 0; ks < KS; ++ks)
                acc = __builtin_amdgcn_mfma_f32_16x16x32_bf16(
                    af[ks], cpf[(nt * KS + ks) * 64 + lane], acc, 0, 0, 0);
#pragma unroll
            for (int r = 0; r < 4; ++r)
                Ps[(row0 + r) * PSTR + nt * 16 + col] = acc[r];
        }
    }
    __syncthreads();  // (2) P ready
    // epilogue: out[row][tstart+tl] = sum_m P[row][noff+m] * F3[row][m]
    constexpr int NL = pi.nl, LMIN = pi.lmin, TSTART = pi.tstart;
    for (int task = tid; task < 64 * NL; task += THREADS) {
        const int r = task / NL;
        const int tl = task - (task / NL) * NL;
        const int l = LMIN + tl;
        const int D3 = 2 * l + 1;
        const int noff = tl * (2 * LMIN + tl);   // sum of prior D3s
        const float* Pr = Ps + r * PSTR + noff;
        const float* f3 = xs + r * NCOEFV + l * l;
        float s = 0.f;
        for (int m = 0; m < D3; ++m) s += Pr[m] * f3[m];
        outg[r * NTRIV + TSTART + tl] = s;
    }
}

template <int... I>
__device__ __forceinline__ void run_pairs(std::integer_sequence<int, I...>, const float* xs,
                                          float* Ps, const unsigned short* __restrict__ cp,
                                          float* __restrict__ outg, int wave, int lane) {
    (pair_step<I>(xs, Ps, cp, outg, wave, lane), ...);
}

__global__ __launch_bounds__(THREADS, 3) void SO3onS2_58420145160629_kernel(
    const float* __restrict__ x, const unsigned short* __restrict__ cp,
    float* __restrict__ out) {
    __shared__ float xs[64 * NCOEFV];   // 20736 B  (fp32 x-tile, 64 rows)
    __shared__ float Ps[64 * PSTR];     // 24832 B  (fp32 P tile, odd stride)
    const int tid = threadIdx.x;
    const int lane = tid & 63, wave = tid >> 6;
    const long b0 = (long)blockIdx.x * 64;

    for (int i = tid; i < 64 * NCOEFV; i += THREADS) xs[i] = x[b0 * NCOEFV + i];
    __syncthreads();
    float* outg = out + b0 * NTRIV;
    run_pairs(std::make_integer_sequence<int, NPAIRS>{}, xs, Ps, cp, outg, wave, lane);
}

extern "C" void kernel_launch(void* const* d_in, const int* in_sizes, int n_in,
                              void* d_out, int out_size, void* d_ws, size_t ws_size,
                              hipStream_t stream) {
    const float* x = (const float*)d_in[0];
    const float* cg = (const float*)d_in[1];
    float* out = (float*)d_out;
    unsigned short* cp = (unsigned short*)d_ws;   // PT.cptot bf16 elements (~640 KB)
    const int B = in_sizes[0] / NCOEFV;           // 131072
    prep_kernel<<<dim3(PT.nft), dim3(64), 0, stream>>>(cg, cp);
    SO3onS2_58420145160629_kernel<<<dim3(B / 64), dim3(THREADS), 0, stream>>>(x, cp, out);
}

// Round 7
// 726.054 us; speedup vs baseline: 1.6403x; 1.6403x over previous
//
#include <hip/hip_runtime.h>
#include <utility>

// SO(3) bispectrum via per-(l1,l2)-pair bf16 MFMA GEMMs.
// out[b,t] = sum_{m1,m2,m} cg[t,m1,m2,m] * F1[b,m1] * F2[b,m2] * F3[b,m]
// R7: 32-row blocks, 512 thr (8 waves = 2 rowslices x 4 colgroups).
//     G built ONCE in LDS (bf16, u32 writes, XOR swizzle, even-padded m1-rows),
//     A-frags via ds_read_b128; P stored TRANSPOSED [n][row] so acc stores are b128;
//     out staged in LDS and written coalesced (R5-verified write path).
//     LDS 70.5 KB -> 2 blocks/CU. 2 barriers/pair; epilogue overlaps next G-build.

#define LMAXV 8
#define NCOEFV 81
#define NTRIV 215
#define CGS 4913          // 17*17*17
#define NPAIRS 45
#define THREADS 512
#define ROWS 32
#define PTSTR 36          // f32 word stride of Pt[n][row] (mult of 4 for b128 align)

typedef float f32x4 __attribute__((ext_vector_type(4)));
typedef __bf16 bf16x8 __attribute__((ext_vector_type(8)));

struct PairInfo {
    int l1, l2, D1, D2, D2p, K, Kpad, KS, lmin, nl, N, NT, tstart, cpbase;
};
struct PairTab { PairInfo p[NPAIRS]; int nft; int cptot; };

constexpr PairTab make_pairs() {
    PairTab tb{};
    int idx = 0, t = 0, cpb = 0, ft = 0;
    for (int l1 = 0; l1 <= LMAXV; ++l1)
        for (int l2 = l1; l2 <= LMAXV; ++l2) {
            PairInfo pi{};
            pi.l1 = l1; pi.l2 = l2;
            pi.D1 = 2 * l1 + 1; pi.D2 = 2 * l2 + 1;
            pi.D2p = pi.D2 + 1;               // even row width -> u32-aligned writes
            pi.K = pi.D1 * pi.D2p;            // logical K incl. zero pad column
            pi.Kpad = (pi.K + 31) & ~31;
            pi.KS = pi.Kpad / 32;
            pi.lmin = l2 - l1;
            int lmax = (l1 + l2 < LMAXV) ? (l1 + l2) : LMAXV;
            pi.nl = lmax - pi.lmin + 1;
            int N = 0;
            for (int l = pi.lmin; l <= lmax; ++l) N += 2 * l + 1;
            pi.N = N;
            pi.NT = (N + 15) / 16;
            pi.tstart = t;
            t += pi.nl;
            pi.cpbase = cpb;
            cpb += pi.NT * pi.KS * 512;       // bf16 elements
            ft += pi.NT * pi.KS;
            tb.p[idx++] = pi;
        }
    tb.nft = ft; tb.cptot = cpb;
    return tb;
}
constexpr PairTab PT = make_pairs();
__device__ const PairTab d_PT = make_pairs();   // runtime-indexable copy for prep

static_assert(PT.p[NPAIRS - 1].tstart + PT.p[NPAIRS - 1].nl == NTRIV, "triple count");
static_assert(PT.p[NPAIRS - 1].Kpad == 320, "max Kpad");

__device__ __forceinline__ unsigned short f2bf(float f) {   // RNE f32 -> bf16 bits
    unsigned u = __float_as_uint(f);
    return (unsigned short)((u + 0x7fffu + ((u >> 16) & 1u)) >> 16);
}

// ---- prep: pack cg (fp32) into fragment-linear bf16 Cp in d_ws, zero-padded.
// One 64-thread block per (pair, nt, ks) tile. Lane l holds
// B[k = ks*32 + (l>>4)*8 + i][n = nt*16 + (l&15)], 8 bf16 = 16 B, stored linearly.
// k decodes as (m1 = k/D2p, m2 = k%D2p); m2 == D2 is the zero pad column.
__global__ __launch_bounds__(64) void prep_kernel(const float* __restrict__ cg,
                                                  unsigned short* __restrict__ cp) {
    int bid = blockIdx.x, lane = threadIdx.x;
    int p = 0, base = 0;
    while (p < NPAIRS - 1 && bid >= base + d_PT.p[p].NT * d_PT.p[p].KS) {
        base += d_PT.p[p].NT * d_PT.p[p].KS; ++p;
    }
    PairInfo pi = d_PT.p[p];
    int local = bid - base;
    int nt = local / pi.KS, ks = local - nt * pi.KS;
    int n = nt * 16 + (lane & 15);
    int kb = ks * 32 + (lane >> 4) * 8;
    int tl = -1, m = 0;
    if (n < pi.N) {
        int off = 0;
        for (int q = 0; q < pi.nl; ++q) {
            int D3 = 2 * (pi.lmin + q) + 1;
            if (n < off + D3) { tl = q; m = n - off; break; }
            off += D3;
        }
    }
    unsigned short vals[8];
#pragma unroll
    for (int i = 0; i < 8; ++i) {
        int k = kb + i;
        float v = 0.f;
        if (tl >= 0 && k < pi.K) {
            int m1 = k / pi.D2p, m2 = k - (k / pi.D2p) * pi.D2p;
            if (m2 < pi.D2)
                v = cg[(long)(pi.tstart + tl) * CGS + (m1 * 17 + m2) * 17 + m];
        }
        vals[i] = f2bf(v);
    }
    *reinterpret_cast<bf16x8*>(cp + pi.cpbase + ((long)(nt * pi.KS + ks) * 64 + lane) * 8) =
        *reinterpret_cast<bf16x8*>(vals);
}

// ---- per-pair step (all shapes compile-time)
template <int P>
__device__ __forceinline__ void pair_step(const float* xs, unsigned short* gs, float* Pt,
                                          float* outl, const unsigned short* __restrict__ cp,
                                          int wave, int lane, int tid) {
    constexpr PairInfo pi = PT.p[P];
    constexpr int D1 = pi.D1, D2 = pi.D2, D2p = pi.D2p, K = pi.K, Kpad = pi.Kpad;
    constexpr int KS = pi.KS, NT = pi.NT, NL = pi.nl, LMIN = pi.lmin, TSTART = pi.tstart;
    constexpr int XB1 = pi.l1 * pi.l1, XB2 = pi.l2 * pi.l2;
    constexpr int W2 = D2p / 2;

    // ---- G build: G[row][j=m1*D2p+m2] = F1*F2 (bf16), u32-paired, XOR-swizzled.
    // Runs in the same barrier-free region as the previous pair's epilogue.
    for (int task = tid; task < ROWS * D1; task += THREADS) {
        const int row = task / D1;
        const int m1 = task - (task / D1) * D1;
        const float* xr = xs + row * NCOEFV;
        const float f1 = xr[XB1 + m1];
        const unsigned rowb = (unsigned)row * (2 * Kpad);
        const unsigned swz = ((unsigned)row & 7) << 4;
        const int j0 = m1 * D2p;
#pragma unroll
        for (int q = 0; q < W2; ++q) {
            const int m2 = 2 * q;
            float a = f1 * xr[XB2 + m2];
            float b = (m2 + 1 < D2) ? f1 * xr[XB2 + m2 + 1] : 0.f;   // compile-time cond
            unsigned pk = (unsigned)f2bf(a) | ((unsigned)f2bf(b) << 16);
            *(unsigned*)((char*)gs + ((rowb + (unsigned)(j0 + m2) * 2) ^ swz)) = pk;
        }
    }
    constexpr int PADW = (Kpad - K) / 2;   // u32 zero-fill of k in [K, Kpad)
    if constexpr (PADW > 0) {
        for (int task = tid; task < ROWS * PADW; task += THREADS) {
            const int row = task / PADW;
            const int q = task - (task / PADW) * PADW;
            const unsigned swz = ((unsigned)row & 7) << 4;
            *(unsigned*)((char*)gs +
                (((unsigned)row * (2 * Kpad) + (unsigned)(K + 2 * q) * 2) ^ swz)) = 0u;
        }
    }
    __syncthreads();  // (1) G ready; prev epilogue's Pt reads drained
    const int rowslice = wave & 1, colgroup = wave >> 1;
    if (colgroup < NT) {          // wave-uniform branch
        bf16x8 af[KS];
        {
            const int row = rowslice * 16 + (lane & 15);
            const unsigned rowb = (unsigned)row * (2 * Kpad);
            const unsigned swz = ((unsigned)row & 7) << 4;
            const unsigned kb = ((unsigned)(lane >> 4)) * 16;
#pragma unroll
            for (int ks = 0; ks < KS; ++ks)
                af[ks] = *(const bf16x8*)((const char*)gs + ((rowb + ks * 64 + kb) ^ swz));
        }
        const bf16x8* cpf = (const bf16x8*)(cp + pi.cpbase);
        const int col = lane & 15;
        const int row0 = rowslice * 16 + ((lane >> 4) << 2);  // C/D: col=lane&15, row=(lane>>4)*4+r
        for (int nt = colgroup; nt < NT; nt += 4) {
            f32x4 acc = {0.f, 0.f, 0.f, 0.f};
#pragma unroll
            for (int ks = 0; ks < KS; ++ks)
                acc = __builtin_amdgcn_mfma_f32_16x16x32_bf16(
                    af[ks], cpf[(nt * KS + ks) * 64 + lane], acc, 0, 0, 0);
            // transposed P: Pt[n][row], contiguous in row -> single b128 store
            *(f32x4*)(Pt + (nt * 16 + col) * PTSTR + row0) = acc;
        }
    }
    __syncthreads();  // (2) Pt complete
    // ---- epilogue: outl[r][TSTART+tl] = sum_m Pt[noff+m][r] * F3[r][m]
    for (int task = tid; task < ROWS * NL; task += THREADS) {
        const int r = task / NL;
        const int tl = task - (task / NL) * NL;
        const int l = LMIN + tl;
        const int D3 = 2 * l + 1;
        const int noff = tl * (2 * LMIN + tl);   // sum of prior D3s
        const float* f3 = xs + r * NCOEFV + l * l;
        const float* Pr = Pt + noff * PTSTR + r;
        float s = 0.f;
        for (int m = 0; m < D3; ++m) s += Pr[m * PTSTR] * f3[m];
        outl[r * NTRIV + TSTART + tl] = s;
    }
}

template <int... I>
__device__ __forceinline__ void run_pairs(std::integer_sequence<int, I...>, const float* xs,
                                          unsigned short* gs, float* Pt, float* outl,
                                          const unsigned short* __restrict__ cp,
                                          int wave, int lane, int tid) {
    (pair_step<I>(xs, gs, Pt, outl, cp, wave, lane, tid), ...);
}

__global__ __launch_bounds__(THREADS, 4) void SO3onS2_58420145160629_kernel(
    const float* __restrict__ x, const unsigned short* __restrict__ cp,
    float* __restrict__ out) {
    __shared__ float xs[ROWS * NCOEFV];          // 10368 B
    __shared__ unsigned short gs[ROWS * 320];    // 20480 B (bf16 G, swizzled)
    __shared__ float Pt[96 * PTSTR];             // 13824 B (transposed P)
    __shared__ float outl[ROWS * NTRIV];         // 27520 B (out staging)
    const int tid = threadIdx.x;
    const int lane = tid & 63, wave = tid >> 6;
    const long b0 = (long)blockIdx.x * ROWS;

    for (int i = tid; i < ROWS * NCOEFV; i += THREADS) xs[i] = x[b0 * NCOEFV + i];
    __syncthreads();
    run_pairs(std::make_integer_sequence<int, NPAIRS>{}, xs, gs, Pt, outl, cp, wave, lane, tid);
    __syncthreads();
    float* og = out + b0 * NTRIV;
    for (int i = tid; i < ROWS * NTRIV; i += THREADS) og[i] = outl[i];   // coalesced
}

extern "C" void kernel_launch(void* const* d_in, const int* in_sizes, int n_in,
                              void* d_out, int out_size, void* d_ws, size_t ws_size,
                              hipStream_t stream) {
    const float* x = (const float*)d_in[0];
    const float* cg = (const float*)d_in[1];
    float* out = (float*)d_out;
    unsigned short* cp = (unsigned short*)d_ws;   // PT.cptot bf16 elements (<1 MB)
    const int B = in_sizes[0] / NCOEFV;           // 131072
    prep_kernel<<<dim3(PT.nft), dim3(64), 0, stream>>>(cg, cp);
    SO3onS2_58420145160629_kernel<<<dim3(B / ROWS), dim3(THREADS), 0, stream>>>(x, cp, out);
}